// Round 10
// baseline (350.832 us; speedup 1.0000x reference)
//
#include <hip/hip_runtime.h>
#include <hip/hip_bf16.h>
#include <math.h>
#include <type_traits>

// ---------------------------------------------------------------------------
// BridgeLayer, 4-dispatch version:
//  1) prep: weight transposes + rmsnorms + Wc=Wsq@Wsk^T (fp32 split-K)
//  2) merged: 6 bf16-MFMA GEMMs (global_load_lds, XCD-swizzled) + u fp32 GEMM
//  3) fused_attn: MFMA flash (S^T softmax, reg-prefetch, LPT) + part1/part3
//  4) epilogue: outS += attn1@Wso ; outR = r + rat@Wro
// B=1,T=1024,N=8,H=8,D_S=1024,D_R=512,TOPK=4
// ---------------------------------------------------------------------------

#define T_DIM 1024
#define N_SLOT 8
#define DS 1024
#define DR 512
#define NH 8
#define DHS 128
#define DHR 64

typedef __attribute__((ext_vector_type(8))) short short8v;
typedef __attribute__((ext_vector_type(4))) float floatx4;

#define GLDS(gptr, lptr)                                                     \
  __builtin_amdgcn_global_load_lds(                                          \
      (__attribute__((address_space(1))) void*)(gptr),                       \
      (__attribute__((address_space(3))) void*)(lptr), 16, 0, 0)

// XCD chunk swizzle: contiguous work slab per XCD (bijection on [0,G)).
__device__ inline int xcd_swz(int b, int G) {
  int per = G >> 3, rem = G & 7;
  int x = b & 7, i = b >> 3;
  return x * per + (x < rem ? x : rem) + i;
}

__device__ inline float bf_lo(unsigned int u) {
  unsigned short x = (unsigned short)(u & 0xffff);
  __hip_bfloat16 b;
  __builtin_memcpy(&b, &x, 2);
  return __bfloat162float(b);
}
__device__ inline float bf_hi(unsigned int u) {
  unsigned short x = (unsigned short)(u >> 16);
  __hip_bfloat16 b;
  __builtin_memcpy(&b, &x, 2);
  return __bfloat162float(b);
}

// ----------------------------------------------- fp32 gemm body (split-K) ---
// Cz = A[M, K/2-slice] @ B-slice. BT: B is [N][K]. BSUM: B = B0 + B1 partials.
template <bool BT, bool BSUM>
__device__ void gemm_f32_body(char* smemraw, const float* __restrict__ A,
                              const float* __restrict__ B, float* __restrict__ C,
                              int M, int N, int K, int bx, int by, int bz) {
  constexpr int BS = 64, TT = 4;
  float(*Ast)[BS + 4] = (float(*)[BS + 4])smemraw;
  float(*Bs)[BS + 4] = (float(*)[BS + 4])(smemraw + 16 * (BS + 4) * 4);
  const int tid = threadIdx.x;
  const int tx = tid & 15, ty = tid >> 4;
  const int row0 = by * BS, col0 = bx * BS;
  const int kbeg = bz * (K >> 1), kend = kbeg + (K >> 1);
  float* Cz = C + (size_t)bz * M * N;
  const size_t bsz = (size_t)K * N;
  float acc[TT][TT] = {};
  constexpr int NF4 = BS * 16 / 4;
  for (int k0 = kbeg; k0 < kend; k0 += 16) {
    __syncthreads();
    for (int l = tid; l < NF4; l += 256) {
      int lr = l >> 2, lk = (l & 3) << 2;
      float4 a4 = *(const float4*)&A[(size_t)(row0 + lr) * K + k0 + lk];
      Ast[lk + 0][lr] = a4.x;
      Ast[lk + 1][lr] = a4.y;
      Ast[lk + 2][lr] = a4.z;
      Ast[lk + 3][lr] = a4.w;
      if (BT) {
        float4 b4 = *(const float4*)&B[(size_t)(col0 + lr) * K + k0 + lk];
        Bs[lk + 0][lr] = b4.x;
        Bs[lk + 1][lr] = b4.y;
        Bs[lk + 2][lr] = b4.z;
        Bs[lk + 3][lr] = b4.w;
      } else {
        int bkk = l / (BS / 4), bc = (l % (BS / 4)) << 2;
        size_t bidx = (size_t)(k0 + bkk) * N + col0 + bc;
        float4 b4 = *(const float4*)&B[bidx];
        if (BSUM) {
          float4 b2 = *(const float4*)&B[bsz + bidx];
          b4.x += b2.x; b4.y += b2.y; b4.z += b2.z; b4.w += b2.w;
        }
        *(float4*)&Bs[bkk][bc] = b4;
      }
    }
    __syncthreads();
#pragma unroll
    for (int kk = 0; kk < 16; ++kk) {
      float av[TT], bv[TT];
      *(float4*)&av[0] = *(const float4*)&Ast[kk][ty * TT];
      *(float4*)&bv[0] = *(const float4*)&Bs[kk][tx * TT];
#pragma unroll
      for (int i = 0; i < TT; ++i)
#pragma unroll
        for (int j = 0; j < TT; ++j) acc[i][j] += av[i] * bv[j];
    }
  }
#pragma unroll
  for (int i = 0; i < TT; ++i) {
    size_t crow = (size_t)(row0 + ty * TT + i) * N + col0;
#pragma unroll
    for (int j = 0; j < TT; j += 4) {
      *(float4*)&Cz[crow + tx * TT + j] =
          make_float4(acc[i][j], acc[i][j + 1], acc[i][j + 2], acc[i][j + 3]);
    }
  }
}

// ---------------------------------------------------------------- dispatch 1
struct TJob { const float* W; __hip_bfloat16* Wt; int K; int N; float scale; int b0; };
struct TJobs { TJob j[8]; };

// [0,4608) transpose; [4608,13824) rmsnorm; [13824,14080) Wc fp32 gemm.
__global__ __launch_bounds__(256) void prep_kernel(
    TJobs jobs, const float* __restrict__ s, const float* __restrict__ r,
    const float* __restrict__ nsw, const float* __restrict__ nrw,
    __hip_bfloat16* __restrict__ s_nb, float* __restrict__ s_n32,
    __hip_bfloat16* __restrict__ r_nb, const float* __restrict__ Wsq,
    const float* __restrict__ Wsk, float* __restrict__ Wc01) {
  __shared__ __align__(16) char smem[8704];
  const int tid = threadIdx.x;
  const int b = blockIdx.x;
  if (b >= 13824) {
    const int lb = b - 13824;
    gemm_f32_body<true, false>(smem, Wsq, Wsk, Wc01, 1024, 512, 1024,
                               lb & 7, (lb & 127) >> 3, lb >> 7);
    return;
  }
  if (b < 4608) {
    float(*t)[33] = (float(*)[33])smem;
    int ji = 0;
#pragma unroll
    for (int q = 1; q < 8; ++q)
      if (b >= jobs.j[q].b0) ji = q;
    const TJob J = jobs.j[ji];
    const int lb = b - J.b0;
    const int nbx = J.N >> 5;
    const int n0 = (lb % nbx) * 32, k0 = (lb / nbx) * 32;
    const int tx = tid & 31, ty = tid >> 5;
#pragma unroll
    for (int i = 0; i < 4; ++i) {
      int kk = ty + i * 8;
      t[kk][tx] = J.W[(size_t)(k0 + kk) * J.N + n0 + tx];
    }
    __syncthreads();
#pragma unroll
    for (int i = 0; i < 4; ++i) {
      int nn = ty + i * 8;
      J.Wt[(size_t)(n0 + nn) * J.K + k0 + tx] = __float2bfloat16(t[tx][nn] * J.scale);
    }
  } else {
    const int blk = b - 4608;
    const bool is_s = blk < 1024;
    const int row = is_s ? blk : blk - 1024;
    const int width = is_s ? DS : DR;
    const float* x = is_s ? s : r;
    const float* w = is_s ? nsw : nrw;
    const size_t base = (size_t)row * width;
    float* red = (float*)smem;
    float ss = 0.f;
    for (int i = tid; i < width; i += 256) {
      float v = x[base + i];
      ss += v * v;
    }
    for (int m = 32; m >= 1; m >>= 1) ss += __shfl_xor(ss, m);
    const int wave = tid >> 6, lane = tid & 63;
    if (lane == 0) red[wave] = ss;
    __syncthreads();
    float total = red[0] + red[1] + red[2] + red[3];
    float scale = rsqrtf(total / (float)width + 1e-6f);
    for (int i = tid; i < width; i += 256) {
      float val = x[base + i] * scale * w[i];
      if (is_s) {
        s_nb[base + i] = __float2bfloat16(val);
        s_n32[base + i] = val;
      } else {
        r_nb[base + i] = __float2bfloat16(val);
      }
    }
  }
}

// ---------------------------------------------------------------- dispatch 2
struct GJob6 { const __hip_bfloat16* A; const __hip_bfloat16* Bt;
               __hip_bfloat16* C; int M; int N; int K; int b0; int trans; };
struct GJobs6 { GJob6 j[6]; };

// blocks [0,1408) = 6 bf16 MFMA jobs (MT=128); [1408,1664) = u fp32 gemm.
__global__ __launch_bounds__(256) void merged_gemm_kernel(
    GJobs6 jobs, const float* __restrict__ s_n32, const float* __restrict__ Wc01,
    float* __restrict__ u01) {
  __shared__ __align__(16) char smem[16384];
  const int sb = xcd_swz(blockIdx.x, gridDim.x);
  if (sb >= 1408) {
    const int lb = sb - 1408;
    gemm_f32_body<false, true>(smem, s_n32, Wc01, u01, 1024, 512, 1024,
                               lb & 7, (lb & 127) >> 3, lb >> 7);
    return;
  }
  int ji = 0;
#pragma unroll
  for (int t = 1; t < 6; ++t)
    if (sb >= jobs.j[t].b0) ji = t;
  const GJob6 J = jobs.j[ji];
  const int lb = sb - J.b0;
  const int nbx = J.N >> 7;
  const int row0 = (lb / nbx) * 128, col0 = (lb % nbx) * 128;
  const int K = J.K;
  __hip_bfloat16(*As)[32] = (__hip_bfloat16(*)[32])smem;
  __hip_bfloat16(*Bs)[32] = (__hip_bfloat16(*)[32])(smem + 8192);
  const int tid = threadIdx.x;
  const int lane = tid & 63, wave = tid >> 6;
  const int wm = wave >> 1, wn = wave & 1;
  const int l15 = lane & 15, l4 = lane >> 4;
  const int dma_r = lane >> 2;
  const int dma_c = (lane & 3) ^ ((lane >> 3) & 3);
  const int rd_sw = (l15 >> 1) & 3;
  floatx4 acc[4][4] = {};
  for (int k0 = 0; k0 < K; k0 += 32) {
    __syncthreads();
#pragma unroll
    for (int i = 0; i < 2; ++i) {
      int seg = wave * 2 + i;
      GLDS(&J.A[(size_t)(row0 + seg * 16 + dma_r) * K + k0 + dma_c * 8], &As[seg * 16][0]);
      GLDS(&J.Bt[(size_t)(col0 + seg * 16 + dma_r) * K + k0 + dma_c * 8], &Bs[seg * 16][0]);
    }
    __syncthreads();
    short8v af[4], bf[4];
#pragma unroll
    for (int i = 0; i < 4; ++i)
      af[i] = *(const short8v*)&As[wm * 64 + i * 16 + l15][(l4 ^ rd_sw) * 8];
#pragma unroll
    for (int j = 0; j < 4; ++j)
      bf[j] = *(const short8v*)&Bs[wn * 64 + j * 16 + l15][(l4 ^ rd_sw) * 8];
#pragma unroll
    for (int i = 0; i < 4; ++i)
#pragma unroll
      for (int j = 0; j < 4; ++j)
        acc[i][j] = __builtin_amdgcn_mfma_f32_16x16x32_bf16(af[i], bf[j], acc[i][j], 0, 0, 0);
  }
  // C/D layout: col = lane&15, row = (lane>>4)*4 + reg  [m89-verified]
#pragma unroll
  for (int i = 0; i < 4; ++i) {
    int rb = row0 + wm * 64 + i * 16 + l4 * 4;
#pragma unroll
    for (int j = 0; j < 4; ++j) {
      int cb = col0 + wn * 64 + j * 16 + l15;
      if (J.trans) {
        __hip_bfloat16 pk[4];
#pragma unroll
        for (int rg = 0; rg < 4; ++rg) pk[rg] = __float2bfloat16(acc[i][j][rg]);
        *(ushort4*)&J.C[(size_t)cb * J.M + rb] = *(const ushort4*)pk;
      } else {
#pragma unroll
        for (int rg = 0; rg < 4; ++rg)
          J.C[(size_t)(rb + rg) * J.N + cb] = __float2bfloat16(acc[i][j][rg]);
      }
    }
  }
}

// ---------------------------------------------------------------- dispatch 3
// [0,1024): flash (LPT order, S^T softmax, reg-prefetched K/V staging);
// [1024,2048): part1+part3.
__global__ __launch_bounds__(256) void fused_attn_kernel(
    const __hip_bfloat16* __restrict__ qb, const __hip_bfloat16* __restrict__ kb,
    const __hip_bfloat16* __restrict__ vbT, __hip_bfloat16* __restrict__ rat,
    const float* __restrict__ s, const float* __restrict__ gv,
    const __hip_bfloat16* __restrict__ q, const __hip_bfloat16* __restrict__ k,
    const __hip_bfloat16* __restrict__ v, const float* __restrict__ r,
    const float* __restrict__ nrw, const float* __restrict__ u0,
    const float* __restrict__ u1, __hip_bfloat16* __restrict__ attn1,
    float* __restrict__ outS) {
  __shared__ __align__(16) char smem[27648];
  const int tid = threadIdx.x;
  if (blockIdx.x < 1024) {
    // ---------------- flash branch ----------------
    __hip_bfloat16(*QP)[72] = (__hip_bfloat16(*)[72])smem;          // Qs then Pb
    __hip_bfloat16(*Ks)[72] = (__hip_bfloat16(*)[72])(smem + 9216);
    __hip_bfloat16(*Vt)[72] = (__hip_bfloat16(*)[72])(smem + 18432);
    const int fb = blockIdx.x;
    const int qt = 127 - (fb >> 3);  // LPT: longest blocks first
    const int h = fb & 7;
    const int qbase = qt * 64;
    const int lane = tid & 63, wave = tid >> 6;
    const int l15 = lane & 15, l4 = lane >> 4;
    const int st = wave * 16;

    for (int g = tid; g < 512; g += 256) {
      int rr = g >> 3, c = (g & 7) * 8;
      *(ulonglong2*)&QP[rr][c] =
          *(const ulonglong2*)&qb[(size_t)(qbase + rr) * DR + h * DHR + c];
    }
    __syncthreads();
    short8v qf[2];  // B-frag: n = l15 = qrow
#pragma unroll
    for (int kk = 0; kk < 2; ++kk)
      qf[kk] = *(const short8v*)&QP[st + l15][kk * 32 + l4 * 8];

    const int myt = (qbase + st + l15) >> 3;
    const int tmin = (qbase + st) >> 3;
    const int tmax = (qbase + st + 15) >> 3;

    float m_r = -1e30f, l_r = 0.f;
    floatx4 o[4] = {};  // O^T: col = l15 = qrow, row = dim

    const int rr0 = tid >> 3, c0 = (tid & 7) * 8;
    const int g1 = tid + 256;
    const int rr1 = g1 >> 3, c1 = (g1 & 7) * 8;
    ulonglong2 kreg0, kreg1, vreg0, vreg1;
    auto loadKV = [&](int p0) {
      kreg0 = *(const ulonglong2*)&kb[(size_t)(p0 + rr0) * DR + h * DHR + c0];
      kreg1 = *(const ulonglong2*)&kb[(size_t)(p0 + rr1) * DR + h * DHR + c1];
      vreg0 = *(const ulonglong2*)&vbT[(size_t)(h * DHR + rr0) * T_DIM + p0 + c0];
      vreg1 = *(const ulonglong2*)&vbT[(size_t)(h * DHR + rr1) * T_DIM + p0 + c1];
    };
    const int ntiles = (((qbase + 63) >> 3) >> 6) + 1;
    loadKV(0);
    for (int pt = 0; pt < ntiles; ++pt) {
      const int p0 = pt << 6;
      __syncthreads();  // previous tile's consumers done (also orders Qs reads)
      *(ulonglong2*)&Ks[rr0][c0] = kreg0;
      *(ulonglong2*)&Ks[rr1][c1] = kreg1;
      *(ulonglong2*)&Vt[rr0][c0] = vreg0;
      *(ulonglong2*)&Vt[rr1][c1] = vreg1;
      if (pt + 1 < ntiles) loadKV((pt + 1) << 6);  // prefetch next tile
      __syncthreads();
      if (p0 > tmax) continue;  // wave-uniform skip
      floatx4 sc[4] = {};
#pragma unroll
      for (int j = 0; j < 4; ++j)
#pragma unroll
        for (int kk = 0; kk < 2; ++kk) {
          short8v kf = *(const short8v*)&Ks[j * 16 + l15][kk * 32 + l4 * 8];
          sc[j] = __builtin_amdgcn_mfma_f32_16x16x32_bf16(kf, qf[kk], sc[j], 0, 0, 0);
        }
      if (p0 + 63 > tmin) {
#pragma unroll
        for (int j = 0; j < 4; ++j)
#pragma unroll
          for (int rg = 0; rg < 4; ++rg)
            if (p0 + j * 16 + l4 * 4 + rg > myt) sc[j][rg] = -1e30f;
      }
      float mx = m_r;
#pragma unroll
      for (int j = 0; j < 4; ++j)
#pragma unroll
        for (int rg = 0; rg < 4; ++rg) mx = fmaxf(mx, sc[j][rg]);
      mx = fmaxf(mx, __shfl_xor(mx, 16));
      mx = fmaxf(mx, __shfl_xor(mx, 32));
      float sum = 0.f;
#pragma unroll
      for (int j = 0; j < 4; ++j)
#pragma unroll
        for (int rg = 0; rg < 4; ++rg) {
          float e = __expf(sc[j][rg] - mx);
          sc[j][rg] = e;
          sum += e;
        }
      sum += __shfl_xor(sum, 16);
      sum += __shfl_xor(sum, 32);
      const float alpha = __expf(m_r - mx);
      l_r = alpha * l_r + sum;
      m_r = mx;
#pragma unroll
      for (int j = 0; j < 4; ++j) {
        __hip_bfloat16 pk[4];
#pragma unroll
        for (int rg = 0; rg < 4; ++rg) pk[rg] = __float2bfloat16(sc[j][rg]);
        *(ushort4*)&QP[st + l15][j * 16 + l4 * 4] = *(const ushort4*)pk;
      }
#pragma unroll
      for (int jd = 0; jd < 4; ++jd) o[jd] *= alpha;
#pragma unroll
      for (int kk = 0; kk < 2; ++kk) {
        short8v pf = *(const short8v*)&QP[st + l15][kk * 32 + l4 * 8];
#pragma unroll
        for (int jd = 0; jd < 4; ++jd) {
          short8v vf = *(const short8v*)&Vt[jd * 16 + l15][kk * 32 + l4 * 8];
          o[jd] = __builtin_amdgcn_mfma_f32_16x16x32_bf16(vf, pf, o[jd], 0, 0, 0);
        }
      }
    }
    const float inv = 1.f / l_r;
    const size_t rbase = (size_t)(qbase + st + l15) * DR + h * DHR;
#pragma unroll
    for (int jd = 0; jd < 4; ++jd) {
      __hip_bfloat16 pk[4];
#pragma unroll
      for (int rg = 0; rg < 4; ++rg) pk[rg] = __float2bfloat16(o[jd][rg] * inv);
      *(ushort4*)&rat[rbase + jd * 16 + l4 * 4] = *(const ushort4*)pk;
    }
  } else {
    // ---------------- part1 + part3 branch ----------------
    float* qs = (float*)smem;                          // 1024 floats
    float(*dots)[8] = (float(*)[8])(smem + 4096);      // [8][8]
    float(*wattn)[8] = (float(*)[8])(smem + 4352);
    float* w8 = (float*)(smem + 4608);
    float* spv = (float*)(smem + 4640);
    float* gateL = (float*)(smem + 4672);
    const int t = blockIdx.x - 1024;
    {
      const unsigned int* q2 = (const unsigned int*)&q[(size_t)t * DS];
      for (int i = tid; i < DS / 2; i += 256) {
        unsigned int pk = q2[i];
        qs[2 * i] = bf_lo(pk);
        qs[2 * i + 1] = bf_hi(pk);
      }
    }
    __syncthreads();
    const int wave = tid >> 6, lane = tid & 63;
#pragma unroll
    for (int e = 0; e < 16; ++e) {
      int pair = wave * 16 + e;
      int h = pair >> 3, n = pair & 7;
      const unsigned int* kr2 =
          (const unsigned int*)&k[((size_t)t * N_SLOT + n) * DS + h * DHS];
      unsigned int pk = kr2[lane];
      float a = qs[h * DHS + 2 * lane] * bf_lo(pk) +
                qs[h * DHS + 2 * lane + 1] * bf_hi(pk);
      for (int m = 32; m >= 1; m >>= 1) a += __shfl_xor(a, m);
      if (lane == 0) dots[h][n] = a;
    }
    const float scale_s = 0.08838834764831845f;  // 128^-0.5
#pragma unroll
    for (int e = 0; e < 2; ++e) {
      const int n = wave * 2 + e;
      const float* rr = &r[((size_t)t * N_SLOT + n) * DR];
      const float* ub0 = &u0[(size_t)t * DR];
      const float* ub1 = &u1[(size_t)t * DR];
      float ssum = 0.f, dot = 0.f;
#pragma unroll
      for (int jj = 0; jj < 8; ++jj) {
        int j = lane + 64 * jj;
        float rv = rr[j];
        ssum += rv * rv;
        dot += rv * nrw[j] * (ub0[j] + ub1[j]);
      }
      for (int m = 32; m >= 1; m >>= 1) {
        ssum += __shfl_xor(ssum, m);
        dot += __shfl_xor(dot, m);
      }
      if (lane == 0) {
        float rs = rsqrtf(ssum / (float)DR + 1e-6f);
        spv[n] = scale_s * rs * dot;
      }
    }
    __syncthreads();
    if (tid < 8) {
      int h = tid;
      float vmax = -1e30f;
      for (int n = 0; n < 8; ++n) vmax = fmaxf(vmax, dots[h][n] * scale_s);
      float sum = 0.f;
      for (int n = 0; n < 8; ++n) {
        float e = __expf(dots[h][n] * scale_s - vmax);
        wattn[h][n] = e;
        sum += e;
      }
      float inv = 1.f / sum;
      for (int n = 0; n < 8; ++n) wattn[h][n] *= inv;
    }
    if (tid == 64) {
      float sv[8];
      for (int n = 0; n < 8; ++n) sv[n] = spv[n];
      bool used[8] = {};
      float vals[4];
      int idxs[4];
      for (int kk = 0; kk < 4; ++kk) {
        float best = -1e30f;
        int bi = 0;
        for (int n = 0; n < 8; ++n)
          if (!used[n] && sv[n] > best) { best = sv[n]; bi = n; }
        used[bi] = true;
        vals[kk] = best;
        idxs[kk] = bi;
      }
      float mx = vals[0];
      float wv[4];
      float sum = 0.f;
      for (int kk = 0; kk < 4; ++kk) {
        wv[kk] = __expf(vals[kk] - mx);
        sum += wv[kk];
      }
      float inv = 1.f / sum;
      for (int n = 0; n < 8; ++n) w8[n] = 0.f;
      for (int kk = 0; kk < 4; ++kk) w8[idxs[kk]] = wv[kk] * inv;
      *gateL = gv[t];
    }
    __syncthreads();
    const float gate = *gateL;
#pragma unroll
    for (int jj = 0; jj < 2; ++jj) {
      int dp = tid + 256 * jj;  // pair index in [0, 512)
      int hh = dp >> 6;
      float a1x = 0.f, a1y = 0.f, a2x = 0.f, a2y = 0.f;
#pragma unroll
      for (int n = 0; n < 8; ++n) {
        unsigned int pv =
            ((const unsigned int*)&v[((size_t)t * N_SLOT + n) * DS])[dp];
        float vx = bf_lo(pv), vy = bf_hi(pv);
        float wa = wattn[hh][n], wb = w8[n];
        a1x += wa * vx; a1y += wa * vy;
        a2x += wb * vx; a2y += wb * vy;
      }
      __hip_bfloat16 pk2[2] = {__float2bfloat16(a1x), __float2bfloat16(a1y)};
      ((unsigned int*)&attn1[(size_t)t * DS])[dp] = *(const unsigned int*)pk2;
      float2 sv = ((const float2*)&s[(size_t)t * DS])[dp];
      ((float2*)&outS[(size_t)t * DS])[dp] =
          make_float2(sv.x + gate * a2x, sv.y + gate * a2y);
    }
  }
}

// ---------------------------------------------------------------- dispatch 4
// [0,64): outS += attn1 @ WsoT (M=1024,N=1024); [64,320): outR = r + rat@WroT.
__global__ __launch_bounds__(256) void epilogue_kernel(
    const __hip_bfloat16* __restrict__ attn1, const __hip_bfloat16* __restrict__ WsoT,
    float* __restrict__ outS, const __hip_bfloat16* __restrict__ ratb,
    const __hip_bfloat16* __restrict__ WroT, float* __restrict__ outR,
    const float* __restrict__ r) {
  __shared__ __align__(16) char smem[16384];
  __hip_bfloat16(*As)[32] = (__hip_bfloat16(*)[32])smem;
  __hip_bfloat16(*Bs)[32] = (__hip_bfloat16(*)[32])(smem + 8192);
  const int sb = xcd_swz(blockIdx.x, gridDim.x);
  const bool wso = (sb < 64);
  const __hip_bfloat16* A = wso ? attn1 : ratb;
  const __hip_bfloat16* Bt = wso ? WsoT : WroT;
  float* C = wso ? outS : outR;
  const int lb = wso ? sb : sb - 64;
  const int N = wso ? 1024 : 512;
  const int K = wso ? 1024 : 512;
  const int nbx = N >> 7;
  const int row0 = (lb / nbx) * 128, col0 = (lb % nbx) * 128;
  const int tid = threadIdx.x;
  const int lane = tid & 63, wave = tid >> 6;
  const int wm = wave >> 1, wn = wave & 1;
  const int l15 = lane & 15, l4 = lane >> 4;
  const int dma_r = lane >> 2;
  const int dma_c = (lane & 3) ^ ((lane >> 3) & 3);
  const int rd_sw = (l15 >> 1) & 3;
  floatx4 acc[4][4] = {};
  for (int k0 = 0; k0 < K; k0 += 32) {
    __syncthreads();
#pragma unroll
    for (int i = 0; i < 2; ++i) {
      int seg = wave * 2 + i;
      GLDS(&A[(size_t)(row0 + seg * 16 + dma_r) * K + k0 + dma_c * 8], &As[seg * 16][0]);
      GLDS(&Bt[(size_t)(col0 + seg * 16 + dma_r) * K + k0 + dma_c * 8], &Bs[seg * 16][0]);
    }
    __syncthreads();
    short8v af[4], bf[4];
#pragma unroll
    for (int i = 0; i < 4; ++i)
      af[i] = *(const short8v*)&As[wm * 64 + i * 16 + l15][(l4 ^ rd_sw) * 8];
#pragma unroll
    for (int j = 0; j < 4; ++j)
      bf[j] = *(const short8v*)&Bs[wn * 64 + j * 16 + l15][(l4 ^ rd_sw) * 8];
#pragma unroll
    for (int i = 0; i < 4; ++i)
#pragma unroll
      for (int j = 0; j < 4; ++j)
        acc[i][j] = __builtin_amdgcn_mfma_f32_16x16x32_bf16(af[i], bf[j], acc[i][j], 0, 0, 0);
  }
#pragma unroll
  for (int i = 0; i < 4; ++i) {
    int rb = row0 + wm * 64 + i * 16 + l4 * 4;
#pragma unroll
    for (int j = 0; j < 4; ++j) {
      int cb = col0 + wn * 64 + j * 16 + l15;
#pragma unroll
      for (int rg = 0; rg < 4; ++rg) {
        size_t idx = (size_t)(rb + rg) * N + cb;
        if (wso)
          C[idx] += acc[i][j][rg];
        else
          C[idx] = r[idx] + acc[i][j][rg];
      }
    }
  }
}

// ----------------------------------------------------------------- launch ---
extern "C" void kernel_launch(void* const* d_in, const int* in_sizes, int n_in,
                              void* d_out, int out_size, void* d_ws,
                              size_t ws_size, hipStream_t stream) {
  const float* s   = (const float*)d_in[0];
  const float* r   = (const float*)d_in[1];
  const float* gv  = (const float*)d_in[2];
  const float* nsw = (const float*)d_in[3];
  const float* nrw = (const float*)d_in[4];
  const float* Wsq = (const float*)d_in[5];
  const float* Wsk = (const float*)d_in[6];
  const float* Wsv = (const float*)d_in[7];
  const float* Wso = (const float*)d_in[8];
  const float* Wrq = (const float*)d_in[9];
  const float* Wrk = (const float*)d_in[10];
  const float* Wrv = (const float*)d_in[11];
  const float* Wro = (const float*)d_in[12];

  float* outS = (float*)d_out;   // 1048576 fp32
  float* outR = outS + 1048576;  // 4194304 fp32

  // ---- workspace carve-up (~85 MB, no overlays) ----
  char* wp = (char*)d_ws;
  float* s_n32 = (float*)wp;                  wp += 1048576 * 4;   // 4 MB
  __hip_bfloat16* k    = (__hip_bfloat16*)wp; wp += 8388608 * 2;   // 16 MB
  __hip_bfloat16* v    = (__hip_bfloat16*)wp; wp += 8388608 * 2;   // 16 MB
  __hip_bfloat16* qrb  = (__hip_bfloat16*)wp; wp += 4194304 * 2;   // 8 MB
  __hip_bfloat16* krb  = (__hip_bfloat16*)wp; wp += 524288 * 2;    // 1 MB
  __hip_bfloat16* vrbT = (__hip_bfloat16*)wp; wp += 524288 * 2;    // 1 MB
  __hip_bfloat16* s_nb = (__hip_bfloat16*)wp; wp += 1048576 * 2;   // 2 MB
  __hip_bfloat16* r_nb = (__hip_bfloat16*)wp; wp += 4194304 * 2;   // 8 MB
  __hip_bfloat16* q    = (__hip_bfloat16*)wp; wp += 1048576 * 2;   // 2 MB
  __hip_bfloat16* attn1b = (__hip_bfloat16*)wp; wp += 1048576 * 2; // 2 MB
  __hip_bfloat16* ratb = (__hip_bfloat16*)wp; wp += 4194304 * 2;   // 8 MB
  float* Wc01 = (float*)wp;                   wp += 1048576 * 4;   // 4 MB (2 partials)
  float* u01  = (float*)wp;                   wp += 1048576 * 4;   // 4 MB (2 partials)
  __hip_bfloat16* WsqT = (__hip_bfloat16*)wp; wp += 1048576 * 2;
  __hip_bfloat16* WskT = (__hip_bfloat16*)wp; wp += 524288 * 2;
  __hip_bfloat16* WsvT = (__hip_bfloat16*)wp; wp += 524288 * 2;
  __hip_bfloat16* WsoT = (__hip_bfloat16*)wp; wp += 1048576 * 2;
  __hip_bfloat16* WrqT = (__hip_bfloat16*)wp; wp += 262144 * 2;
  __hip_bfloat16* WrkT = (__hip_bfloat16*)wp; wp += 524288 * 2;
  __hip_bfloat16* WrvT = (__hip_bfloat16*)wp; wp += 524288 * 2;
  __hip_bfloat16* WroT = (__hip_bfloat16*)wp; wp += 262144 * 2;

  float* u0 = u01;
  float* u1 = u01 + 524288;

  // 1) prep: transposes (Wrq pre-scaled 2^-3) + rmsnorms + Wc fp32 gemm
  TJobs jobs = {{
      {Wsq, WsqT, 1024, 1024, 1.f, 0},
      {Wsk, WskT, 512, 1024, 1.f, 1024},
      {Wsv, WsvT, 512, 1024, 1.f, 1536},
      {Wso, WsoT, 1024, 1024, 1.f, 2048},
      {Wrq, WrqT, 512, 512, 0.125f, 3072},
      {Wrk, WrkT, 1024, 512, 1.f, 3328},
      {Wrv, WrvT, 1024, 512, 1.f, 3840},
      {Wro, WroT, 512, 512, 1.f, 4352},
  }};
  prep_kernel<<<14080, 256, 0, stream>>>(jobs, s, r, nsw, nrw, s_nb, s_n32, r_nb,
                                         Wsq, Wsk, Wc01);

  // 2) merged: 6 bf16 MFMA gemms + u fp32 gemm
  GJobs6 g6 = {{
      {r_nb, WskT, k, 8192, 1024, 512, 0, 0},      // 512 blocks
      {r_nb, WsvT, v, 8192, 1024, 512, 512, 0},    // 512
      {r_nb, WrqT, qrb, 8192, 512, 512, 1024, 0},  // 256
      {s_nb, WsqT, q, 1024, 1024, 1024, 1280, 0},  // 64
      {s_nb, WrkT, krb, 1024, 512, 1024, 1344, 0}, // 32
      {s_nb, WrvT, vrbT, 1024, 512, 1024, 1376, 1},// 32 (trans -> [512][1024])
  }};
  merged_gemm_kernel<<<1664, 256, 0, stream>>>(g6, s_n32, Wc01, u01);

  // 3) fused attention: flash (LPT+prefetch) + part1/part3
  fused_attn_kernel<<<2048, 256, 0, stream>>>(qrb, krb, vrbT, ratb, s, gv, q, k,
                                              v, r, nrw, u0, u1, attn1b, outS);

  // 4) epilogue: outS += attn1@Wso ; outR = r + rat@Wro
  epilogue_kernel<<<320, 256, 0, stream>>>(attn1b, WsoT, outS, ratb, WroT, outR, r);
}

// Round 11
// 307.460 us; speedup vs baseline: 1.1411x; 1.1411x over previous
//
#include <hip/hip_runtime.h>
#include <hip/hip_bf16.h>
#include <math.h>
#include <type_traits>

// ---------------------------------------------------------------------------
// BridgeLayer, 4-dispatch version (per-JOB XCD swizzle):
//  1) prep: weight transposes + rmsnorms + Wc=Wsq@Wsk^T (fp32 split-K)
//  2) merged: 6 bf16-MFMA GEMMs (global_load_lds) + u fp32 GEMM
//  3) fused_attn: MFMA flash (S^T softmax, reg-prefetch, LPT) + part1/part3
//  4) epilogue: outS += attn1@Wso ; outR = r + rat@Wro
// B=1,T=1024,N=8,H=8,D_S=1024,D_R=512,TOPK=4
// ---------------------------------------------------------------------------

#define T_DIM 1024
#define N_SLOT 8
#define DS 1024
#define DR 512
#define NH 8
#define DHS 128
#define DHR 64

typedef __attribute__((ext_vector_type(8))) short short8v;
typedef __attribute__((ext_vector_type(4))) float floatx4;

#define GLDS(gptr, lptr)                                                     \
  __builtin_amdgcn_global_load_lds(                                          \
      (__attribute__((address_space(1))) void*)(gptr),                       \
      (__attribute__((address_space(3))) void*)(lptr), 16, 0, 0)

// Per-JOB XCD chunk swizzle (bijection on [0,G)): job-local block lb (whose
// XCD is lb%8 since job bases are multiples of 8) gets a contiguous slab of
// the job's work ids -> per-XCD L2 slab locality WITHOUT cross-job imbalance.
__device__ inline int xcd_swz(int b, int G) {
  int per = G >> 3, rem = G & 7;
  int x = b & 7, i = b >> 3;
  return x * per + (x < rem ? x : rem) + i;
}

__device__ inline float bf_lo(unsigned int u) {
  unsigned short x = (unsigned short)(u & 0xffff);
  __hip_bfloat16 b;
  __builtin_memcpy(&b, &x, 2);
  return __bfloat162float(b);
}
__device__ inline float bf_hi(unsigned int u) {
  unsigned short x = (unsigned short)(u >> 16);
  __hip_bfloat16 b;
  __builtin_memcpy(&b, &x, 2);
  return __bfloat162float(b);
}

// ----------------------------------------------- fp32 gemm body (split-K) ---
template <bool BT, bool BSUM>
__device__ void gemm_f32_body(char* smemraw, const float* __restrict__ A,
                              const float* __restrict__ B, float* __restrict__ C,
                              int M, int N, int K, int bx, int by, int bz) {
  constexpr int BS = 64, TT = 4;
  float(*Ast)[BS + 4] = (float(*)[BS + 4])smemraw;
  float(*Bs)[BS + 4] = (float(*)[BS + 4])(smemraw + 16 * (BS + 4) * 4);
  const int tid = threadIdx.x;
  const int tx = tid & 15, ty = tid >> 4;
  const int row0 = by * BS, col0 = bx * BS;
  const int kbeg = bz * (K >> 1), kend = kbeg + (K >> 1);
  float* Cz = C + (size_t)bz * M * N;
  const size_t bsz = (size_t)K * N;
  float acc[TT][TT] = {};
  constexpr int NF4 = BS * 16 / 4;
  for (int k0 = kbeg; k0 < kend; k0 += 16) {
    __syncthreads();
    for (int l = tid; l < NF4; l += 256) {
      int lr = l >> 2, lk = (l & 3) << 2;
      float4 a4 = *(const float4*)&A[(size_t)(row0 + lr) * K + k0 + lk];
      Ast[lk + 0][lr] = a4.x;
      Ast[lk + 1][lr] = a4.y;
      Ast[lk + 2][lr] = a4.z;
      Ast[lk + 3][lr] = a4.w;
      if (BT) {
        float4 b4 = *(const float4*)&B[(size_t)(col0 + lr) * K + k0 + lk];
        Bs[lk + 0][lr] = b4.x;
        Bs[lk + 1][lr] = b4.y;
        Bs[lk + 2][lr] = b4.z;
        Bs[lk + 3][lr] = b4.w;
      } else {
        int bkk = l / (BS / 4), bc = (l % (BS / 4)) << 2;
        size_t bidx = (size_t)(k0 + bkk) * N + col0 + bc;
        float4 b4 = *(const float4*)&B[bidx];
        if (BSUM) {
          float4 b2 = *(const float4*)&B[bsz + bidx];
          b4.x += b2.x; b4.y += b2.y; b4.z += b2.z; b4.w += b2.w;
        }
        *(float4*)&Bs[bkk][bc] = b4;
      }
    }
    __syncthreads();
#pragma unroll
    for (int kk = 0; kk < 16; ++kk) {
      float av[TT], bv[TT];
      *(float4*)&av[0] = *(const float4*)&Ast[kk][ty * TT];
      *(float4*)&bv[0] = *(const float4*)&Bs[kk][tx * TT];
#pragma unroll
      for (int i = 0; i < TT; ++i)
#pragma unroll
        for (int j = 0; j < TT; ++j) acc[i][j] += av[i] * bv[j];
    }
  }
#pragma unroll
  for (int i = 0; i < TT; ++i) {
    size_t crow = (size_t)(row0 + ty * TT + i) * N + col0;
#pragma unroll
    for (int j = 0; j < TT; j += 4) {
      *(float4*)&Cz[crow + tx * TT + j] =
          make_float4(acc[i][j], acc[i][j + 1], acc[i][j + 2], acc[i][j + 3]);
    }
  }
}

// ---------------------------------------------------------------- dispatch 1
struct TJob { const float* W; __hip_bfloat16* Wt; int K; int N; float scale; int b0; };
struct TJobs { TJob j[8]; };

// [0,4608) transpose; [4608,13824) rmsnorm; [13824,14080) Wc fp32 gemm.
__global__ __launch_bounds__(256) void prep_kernel(
    TJobs jobs, const float* __restrict__ s, const float* __restrict__ r,
    const float* __restrict__ nsw, const float* __restrict__ nrw,
    __hip_bfloat16* __restrict__ s_nb, float* __restrict__ s_n32,
    __hip_bfloat16* __restrict__ r_nb, const float* __restrict__ Wsq,
    const float* __restrict__ Wsk, float* __restrict__ Wc01) {
  __shared__ __align__(16) char smem[8704];
  const int tid = threadIdx.x;
  const int b = blockIdx.x;
  if (b >= 13824) {
    const int lb = b - 13824;
    gemm_f32_body<true, false>(smem, Wsq, Wsk, Wc01, 1024, 512, 1024,
                               lb & 7, (lb & 127) >> 3, lb >> 7);
    return;
  }
  if (b < 4608) {
    float(*t)[33] = (float(*)[33])smem;
    int ji = 0;
#pragma unroll
    for (int q = 1; q < 8; ++q)
      if (b >= jobs.j[q].b0) ji = q;
    const TJob J = jobs.j[ji];
    const int lb = b - J.b0;
    const int nbx = J.N >> 5;
    const int n0 = (lb % nbx) * 32, k0 = (lb / nbx) * 32;
    const int tx = tid & 31, ty = tid >> 5;
#pragma unroll
    for (int i = 0; i < 4; ++i) {
      int kk = ty + i * 8;
      t[kk][tx] = J.W[(size_t)(k0 + kk) * J.N + n0 + tx];
    }
    __syncthreads();
#pragma unroll
    for (int i = 0; i < 4; ++i) {
      int nn = ty + i * 8;
      J.Wt[(size_t)(n0 + nn) * J.K + k0 + tx] = __float2bfloat16(t[tx][nn] * J.scale);
    }
  } else {
    const int blk = b - 4608;
    const bool is_s = blk < 1024;
    const int row = is_s ? blk : blk - 1024;
    const int width = is_s ? DS : DR;
    const float* x = is_s ? s : r;
    const float* w = is_s ? nsw : nrw;
    const size_t base = (size_t)row * width;
    float* red = (float*)smem;
    float ss = 0.f;
    for (int i = tid; i < width; i += 256) {
      float v = x[base + i];
      ss += v * v;
    }
    for (int m = 32; m >= 1; m >>= 1) ss += __shfl_xor(ss, m);
    const int wave = tid >> 6, lane = tid & 63;
    if (lane == 0) red[wave] = ss;
    __syncthreads();
    float total = red[0] + red[1] + red[2] + red[3];
    float scale = rsqrtf(total / (float)width + 1e-6f);
    for (int i = tid; i < width; i += 256) {
      float val = x[base + i] * scale * w[i];
      if (is_s) {
        s_nb[base + i] = __float2bfloat16(val);
        s_n32[base + i] = val;
      } else {
        r_nb[base + i] = __float2bfloat16(val);
      }
    }
  }
}

// ---------------------------------------------------------------- dispatch 2
struct GJob6 { const __hip_bfloat16* A; const __hip_bfloat16* Bt;
               __hip_bfloat16* C; int M; int N; int K; int b0; int nb; int trans; };
struct GJobs6 { GJob6 j[6]; };

// blocks [0,1408) = 6 bf16 MFMA jobs (MT=128); [1408,1664) = u fp32 gemm.
// Job chosen from RAW blockIdx (job bases %8==0 -> each job round-robins all
// XCDs); per-job xcd_swz on the local id for L2 slab locality.
__global__ __launch_bounds__(256) void merged_gemm_kernel(
    GJobs6 jobs, const float* __restrict__ s_n32, const float* __restrict__ Wc01,
    float* __restrict__ u01) {
  __shared__ __align__(16) char smem[16384];
  const int b = blockIdx.x;
  if (b >= 1408) {
    const int lb = xcd_swz(b - 1408, 256);
    gemm_f32_body<false, true>(smem, s_n32, Wc01, u01, 1024, 512, 1024,
                               lb & 7, (lb & 127) >> 3, lb >> 7);
    return;
  }
  int ji = 0;
#pragma unroll
  for (int t = 1; t < 6; ++t)
    if (b >= jobs.j[t].b0) ji = t;
  const GJob6 J = jobs.j[ji];
  const int lb = xcd_swz(b - J.b0, J.nb);
  const int nbx = J.N >> 7;
  const int row0 = (lb / nbx) * 128, col0 = (lb % nbx) * 128;
  const int K = J.K;
  __hip_bfloat16(*As)[32] = (__hip_bfloat16(*)[32])smem;
  __hip_bfloat16(*Bs)[32] = (__hip_bfloat16(*)[32])(smem + 8192);
  const int tid = threadIdx.x;
  const int lane = tid & 63, wave = tid >> 6;
  const int wm = wave >> 1, wn = wave & 1;
  const int l15 = lane & 15, l4 = lane >> 4;
  const int dma_r = lane >> 2;
  const int dma_c = (lane & 3) ^ ((lane >> 3) & 3);
  const int rd_sw = (l15 >> 1) & 3;
  floatx4 acc[4][4] = {};
  for (int k0 = 0; k0 < K; k0 += 32) {
    __syncthreads();
#pragma unroll
    for (int i = 0; i < 2; ++i) {
      int seg = wave * 2 + i;
      GLDS(&J.A[(size_t)(row0 + seg * 16 + dma_r) * K + k0 + dma_c * 8], &As[seg * 16][0]);
      GLDS(&J.Bt[(size_t)(col0 + seg * 16 + dma_r) * K + k0 + dma_c * 8], &Bs[seg * 16][0]);
    }
    __syncthreads();
    short8v af[4], bf[4];
#pragma unroll
    for (int i = 0; i < 4; ++i)
      af[i] = *(const short8v*)&As[wm * 64 + i * 16 + l15][(l4 ^ rd_sw) * 8];
#pragma unroll
    for (int j = 0; j < 4; ++j)
      bf[j] = *(const short8v*)&Bs[wn * 64 + j * 16 + l15][(l4 ^ rd_sw) * 8];
#pragma unroll
    for (int i = 0; i < 4; ++i)
#pragma unroll
      for (int j = 0; j < 4; ++j)
        acc[i][j] = __builtin_amdgcn_mfma_f32_16x16x32_bf16(af[i], bf[j], acc[i][j], 0, 0, 0);
  }
  // C/D layout: col = lane&15, row = (lane>>4)*4 + reg  [m89-verified]
#pragma unroll
  for (int i = 0; i < 4; ++i) {
    int rb = row0 + wm * 64 + i * 16 + l4 * 4;
#pragma unroll
    for (int j = 0; j < 4; ++j) {
      int cb = col0 + wn * 64 + j * 16 + l15;
      if (J.trans) {
        __hip_bfloat16 pk[4];
#pragma unroll
        for (int rg = 0; rg < 4; ++rg) pk[rg] = __float2bfloat16(acc[i][j][rg]);
        *(ushort4*)&J.C[(size_t)cb * J.M + rb] = *(const ushort4*)pk;
      } else {
#pragma unroll
        for (int rg = 0; rg < 4; ++rg)
          J.C[(size_t)(rb + rg) * J.N + cb] = __float2bfloat16(acc[i][j][rg]);
      }
    }
  }
}

// ---------------------------------------------------------------- dispatch 3
// [0,1024): flash (LPT order, S^T softmax, reg-prefetched K/V staging);
// [1024,2048): part1+part3.
__global__ __launch_bounds__(256) void fused_attn_kernel(
    const __hip_bfloat16* __restrict__ qb, const __hip_bfloat16* __restrict__ kb,
    const __hip_bfloat16* __restrict__ vbT, __hip_bfloat16* __restrict__ rat,
    const float* __restrict__ s, const float* __restrict__ gv,
    const __hip_bfloat16* __restrict__ q, const __hip_bfloat16* __restrict__ k,
    const __hip_bfloat16* __restrict__ v, const float* __restrict__ r,
    const float* __restrict__ nrw, const float* __restrict__ u0,
    const float* __restrict__ u1, __hip_bfloat16* __restrict__ attn1,
    float* __restrict__ outS) {
  __shared__ __align__(16) char smem[27648];
  const int tid = threadIdx.x;
  if (blockIdx.x < 1024) {
    // ---------------- flash branch ----------------
    __hip_bfloat16(*QP)[72] = (__hip_bfloat16(*)[72])smem;          // Qs then Pb
    __hip_bfloat16(*Ks)[72] = (__hip_bfloat16(*)[72])(smem + 9216);
    __hip_bfloat16(*Vt)[72] = (__hip_bfloat16(*)[72])(smem + 18432);
    const int fb = blockIdx.x;
    const int qt = 127 - (fb >> 3);  // LPT: longest blocks first
    const int h = fb & 7;
    const int qbase = qt * 64;
    const int lane = tid & 63, wave = tid >> 6;
    const int l15 = lane & 15, l4 = lane >> 4;
    const int st = wave * 16;

    for (int g = tid; g < 512; g += 256) {
      int rr = g >> 3, c = (g & 7) * 8;
      *(ulonglong2*)&QP[rr][c] =
          *(const ulonglong2*)&qb[(size_t)(qbase + rr) * DR + h * DHR + c];
    }
    __syncthreads();
    short8v qf[2];  // B-frag: n = l15 = qrow
#pragma unroll
    for (int kk = 0; kk < 2; ++kk)
      qf[kk] = *(const short8v*)&QP[st + l15][kk * 32 + l4 * 8];

    const int myt = (qbase + st + l15) >> 3;
    const int tmin = (qbase + st) >> 3;
    const int tmax = (qbase + st + 15) >> 3;

    float m_r = -1e30f, l_r = 0.f;
    floatx4 o[4] = {};  // O^T: col = l15 = qrow, row = dim

    const int rr0 = tid >> 3, c0 = (tid & 7) * 8;
    const int g1 = tid + 256;
    const int rr1 = g1 >> 3, c1 = (g1 & 7) * 8;
    ulonglong2 kreg0, kreg1, vreg0, vreg1;
    auto loadKV = [&](int p0) {
      kreg0 = *(const ulonglong2*)&kb[(size_t)(p0 + rr0) * DR + h * DHR + c0];
      kreg1 = *(const ulonglong2*)&kb[(size_t)(p0 + rr1) * DR + h * DHR + c1];
      vreg0 = *(const ulonglong2*)&vbT[(size_t)(h * DHR + rr0) * T_DIM + p0 + c0];
      vreg1 = *(const ulonglong2*)&vbT[(size_t)(h * DHR + rr1) * T_DIM + p0 + c1];
    };
    const int ntiles = (((qbase + 63) >> 3) >> 6) + 1;
    loadKV(0);
    for (int pt = 0; pt < ntiles; ++pt) {
      const int p0 = pt << 6;
      __syncthreads();  // previous tile's consumers done (also orders Qs reads)
      *(ulonglong2*)&Ks[rr0][c0] = kreg0;
      *(ulonglong2*)&Ks[rr1][c1] = kreg1;
      *(ulonglong2*)&Vt[rr0][c0] = vreg0;
      *(ulonglong2*)&Vt[rr1][c1] = vreg1;
      if (pt + 1 < ntiles) loadKV((pt + 1) << 6);  // prefetch next tile
      __syncthreads();
      if (p0 > tmax) continue;  // wave-uniform skip
      floatx4 sc[4] = {};
#pragma unroll
      for (int j = 0; j < 4; ++j)
#pragma unroll
        for (int kk = 0; kk < 2; ++kk) {
          short8v kf = *(const short8v*)&Ks[j * 16 + l15][kk * 32 + l4 * 8];
          sc[j] = __builtin_amdgcn_mfma_f32_16x16x32_bf16(kf, qf[kk], sc[j], 0, 0, 0);
        }
      if (p0 + 63 > tmin) {
#pragma unroll
        for (int j = 0; j < 4; ++j)
#pragma unroll
          for (int rg = 0; rg < 4; ++rg)
            if (p0 + j * 16 + l4 * 4 + rg > myt) sc[j][rg] = -1e30f;
      }
      float mx = m_r;
#pragma unroll
      for (int j = 0; j < 4; ++j)
#pragma unroll
        for (int rg = 0; rg < 4; ++rg) mx = fmaxf(mx, sc[j][rg]);
      mx = fmaxf(mx, __shfl_xor(mx, 16));
      mx = fmaxf(mx, __shfl_xor(mx, 32));
      float sum = 0.f;
#pragma unroll
      for (int j = 0; j < 4; ++j)
#pragma unroll
        for (int rg = 0; rg < 4; ++rg) {
          float e = __expf(sc[j][rg] - mx);
          sc[j][rg] = e;
          sum += e;
        }
      sum += __shfl_xor(sum, 16);
      sum += __shfl_xor(sum, 32);
      const float alpha = __expf(m_r - mx);
      l_r = alpha * l_r + sum;
      m_r = mx;
#pragma unroll
      for (int j = 0; j < 4; ++j) {
        __hip_bfloat16 pk[4];
#pragma unroll
        for (int rg = 0; rg < 4; ++rg) pk[rg] = __float2bfloat16(sc[j][rg]);
        *(ushort4*)&QP[st + l15][j * 16 + l4 * 4] = *(const ushort4*)pk;
      }
#pragma unroll
      for (int jd = 0; jd < 4; ++jd) o[jd] *= alpha;
#pragma unroll
      for (int kk = 0; kk < 2; ++kk) {
        short8v pf = *(const short8v*)&QP[st + l15][kk * 32 + l4 * 8];
#pragma unroll
        for (int jd = 0; jd < 4; ++jd) {
          short8v vf = *(const short8v*)&Vt[jd * 16 + l15][kk * 32 + l4 * 8];
          o[jd] = __builtin_amdgcn_mfma_f32_16x16x32_bf16(vf, pf, o[jd], 0, 0, 0);
        }
      }
    }
    const float inv = 1.f / l_r;
    const size_t rbase = (size_t)(qbase + st + l15) * DR + h * DHR;
#pragma unroll
    for (int jd = 0; jd < 4; ++jd) {
      __hip_bfloat16 pk[4];
#pragma unroll
      for (int rg = 0; rg < 4; ++rg) pk[rg] = __float2bfloat16(o[jd][rg] * inv);
      *(ushort4*)&rat[rbase + jd * 16 + l4 * 4] = *(const ushort4*)pk;
    }
  } else {
    // ---------------- part1 + part3 branch ----------------
    float* qs = (float*)smem;                          // 1024 floats
    float(*dots)[8] = (float(*)[8])(smem + 4096);      // [8][8]
    float(*wattn)[8] = (float(*)[8])(smem + 4352);
    float* w8 = (float*)(smem + 4608);
    float* spv = (float*)(smem + 4640);
    float* gateL = (float*)(smem + 4672);
    const int t = blockIdx.x - 1024;
    {
      const unsigned int* q2 = (const unsigned int*)&q[(size_t)t * DS];
      for (int i = tid; i < DS / 2; i += 256) {
        unsigned int pk = q2[i];
        qs[2 * i] = bf_lo(pk);
        qs[2 * i + 1] = bf_hi(pk);
      }
    }
    __syncthreads();
    const int wave = tid >> 6, lane = tid & 63;
#pragma unroll
    for (int e = 0; e < 16; ++e) {
      int pair = wave * 16 + e;
      int h = pair >> 3, n = pair & 7;
      const unsigned int* kr2 =
          (const unsigned int*)&k[((size_t)t * N_SLOT + n) * DS + h * DHS];
      unsigned int pk = kr2[lane];
      float a = qs[h * DHS + 2 * lane] * bf_lo(pk) +
                qs[h * DHS + 2 * lane + 1] * bf_hi(pk);
      for (int m = 32; m >= 1; m >>= 1) a += __shfl_xor(a, m);
      if (lane == 0) dots[h][n] = a;
    }
    const float scale_s = 0.08838834764831845f;  // 128^-0.5
#pragma unroll
    for (int e = 0; e < 2; ++e) {
      const int n = wave * 2 + e;
      const float* rr = &r[((size_t)t * N_SLOT + n) * DR];
      const float* ub0 = &u0[(size_t)t * DR];
      const float* ub1 = &u1[(size_t)t * DR];
      float ssum = 0.f, dot = 0.f;
#pragma unroll
      for (int jj = 0; jj < 8; ++jj) {
        int j = lane + 64 * jj;
        float rv = rr[j];
        ssum += rv * rv;
        dot += rv * nrw[j] * (ub0[j] + ub1[j]);
      }
      for (int m = 32; m >= 1; m >>= 1) {
        ssum += __shfl_xor(ssum, m);
        dot += __shfl_xor(dot, m);
      }
      if (lane == 0) {
        float rs = rsqrtf(ssum / (float)DR + 1e-6f);
        spv[n] = scale_s * rs * dot;
      }
    }
    __syncthreads();
    if (tid < 8) {
      int h = tid;
      float vmax = -1e30f;
      for (int n = 0; n < 8; ++n) vmax = fmaxf(vmax, dots[h][n] * scale_s);
      float sum = 0.f;
      for (int n = 0; n < 8; ++n) {
        float e = __expf(dots[h][n] * scale_s - vmax);
        wattn[h][n] = e;
        sum += e;
      }
      float inv = 1.f / sum;
      for (int n = 0; n < 8; ++n) wattn[h][n] *= inv;
    }
    if (tid == 64) {
      float sv[8];
      for (int n = 0; n < 8; ++n) sv[n] = spv[n];
      bool used[8] = {};
      float vals[4];
      int idxs[4];
      for (int kk = 0; kk < 4; ++kk) {
        float best = -1e30f;
        int bi = 0;
        for (int n = 0; n < 8; ++n)
          if (!used[n] && sv[n] > best) { best = sv[n]; bi = n; }
        used[bi] = true;
        vals[kk] = best;
        idxs[kk] = bi;
      }
      float mx = vals[0];
      float wv[4];
      float sum = 0.f;
      for (int kk = 0; kk < 4; ++kk) {
        wv[kk] = __expf(vals[kk] - mx);
        sum += wv[kk];
      }
      float inv = 1.f / sum;
      for (int n = 0; n < 8; ++n) w8[n] = 0.f;
      for (int kk = 0; kk < 4; ++kk) w8[idxs[kk]] = wv[kk] * inv;
      *gateL = gv[t];
    }
    __syncthreads();
    const float gate = *gateL;
#pragma unroll
    for (int jj = 0; jj < 2; ++jj) {
      int dp = tid + 256 * jj;  // pair index in [0, 512)
      int hh = dp >> 6;
      float a1x = 0.f, a1y = 0.f, a2x = 0.f, a2y = 0.f;
#pragma unroll
      for (int n = 0; n < 8; ++n) {
        unsigned int pv =
            ((const unsigned int*)&v[((size_t)t * N_SLOT + n) * DS])[dp];
        float vx = bf_lo(pv), vy = bf_hi(pv);
        float wa = wattn[hh][n], wb = w8[n];
        a1x += wa * vx; a1y += wa * vy;
        a2x += wb * vx; a2y += wb * vy;
      }
      __hip_bfloat16 pk2[2] = {__float2bfloat16(a1x), __float2bfloat16(a1y)};
      ((unsigned int*)&attn1[(size_t)t * DS])[dp] = *(const unsigned int*)pk2;
      float2 sv = ((const float2*)&s[(size_t)t * DS])[dp];
      ((float2*)&outS[(size_t)t * DS])[dp] =
          make_float2(sv.x + gate * a2x, sv.y + gate * a2y);
    }
  }
}

// ---------------------------------------------------------------- dispatch 4
// [0,64): outS += attn1 @ WsoT; [64,320): outR = r + rat@WroT.
// Job from RAW blockIdx; per-job swizzle on local id.
__global__ __launch_bounds__(256) void epilogue_kernel(
    const __hip_bfloat16* __restrict__ attn1, const __hip_bfloat16* __restrict__ WsoT,
    float* __restrict__ outS, const __hip_bfloat16* __restrict__ ratb,
    const __hip_bfloat16* __restrict__ WroT, float* __restrict__ outR,
    const float* __restrict__ r) {
  __shared__ __align__(16) char smem[16384];
  __hip_bfloat16(*As)[32] = (__hip_bfloat16(*)[32])smem;
  __hip_bfloat16(*Bs)[32] = (__hip_bfloat16(*)[32])(smem + 8192);
  const int b = blockIdx.x;
  const bool wso = (b < 64);
  const __hip_bfloat16* A = wso ? attn1 : ratb;
  const __hip_bfloat16* Bt = wso ? WsoT : WroT;
  float* C = wso ? outS : outR;
  const int lb = wso ? xcd_swz(b, 64) : xcd_swz(b - 64, 256);
  const int N = wso ? 1024 : 512;
  const int K = wso ? 1024 : 512;
  const int nbx = N >> 7;
  const int row0 = (lb / nbx) * 128, col0 = (lb % nbx) * 128;
  const int tid = threadIdx.x;
  const int lane = tid & 63, wave = tid >> 6;
  const int wm = wave >> 1, wn = wave & 1;
  const int l15 = lane & 15, l4 = lane >> 4;
  const int dma_r = lane >> 2;
  const int dma_c = (lane & 3) ^ ((lane >> 3) & 3);
  const int rd_sw = (l15 >> 1) & 3;
  floatx4 acc[4][4] = {};
  for (int k0 = 0; k0 < K; k0 += 32) {
    __syncthreads();
#pragma unroll
    for (int i = 0; i < 2; ++i) {
      int seg = wave * 2 + i;
      GLDS(&A[(size_t)(row0 + seg * 16 + dma_r) * K + k0 + dma_c * 8], &As[seg * 16][0]);
      GLDS(&Bt[(size_t)(col0 + seg * 16 + dma_r) * K + k0 + dma_c * 8], &Bs[seg * 16][0]);
    }
    __syncthreads();
    short8v af[4], bf[4];
#pragma unroll
    for (int i = 0; i < 4; ++i)
      af[i] = *(const short8v*)&As[wm * 64 + i * 16 + l15][(l4 ^ rd_sw) * 8];
#pragma unroll
    for (int j = 0; j < 4; ++j)
      bf[j] = *(const short8v*)&Bs[wn * 64 + j * 16 + l15][(l4 ^ rd_sw) * 8];
#pragma unroll
    for (int i = 0; i < 4; ++i)
#pragma unroll
      for (int j = 0; j < 4; ++j)
        acc[i][j] = __builtin_amdgcn_mfma_f32_16x16x32_bf16(af[i], bf[j], acc[i][j], 0, 0, 0);
  }
#pragma unroll
  for (int i = 0; i < 4; ++i) {
    int rb = row0 + wm * 64 + i * 16 + l4 * 4;
#pragma unroll
    for (int j = 0; j < 4; ++j) {
      int cb = col0 + wn * 64 + j * 16 + l15;
#pragma unroll
      for (int rg = 0; rg < 4; ++rg) {
        size_t idx = (size_t)(rb + rg) * N + cb;
        if (wso)
          C[idx] += acc[i][j][rg];
        else
          C[idx] = r[idx] + acc[i][j][rg];
      }
    }
  }
}

// ----------------------------------------------------------------- launch ---
extern "C" void kernel_launch(void* const* d_in, const int* in_sizes, int n_in,
                              void* d_out, int out_size, void* d_ws,
                              size_t ws_size, hipStream_t stream) {
  const float* s   = (const float*)d_in[0];
  const float* r   = (const float*)d_in[1];
  const float* gv  = (const float*)d_in[2];
  const float* nsw = (const float*)d_in[3];
  const float* nrw = (const float*)d_in[4];
  const float* Wsq = (const float*)d_in[5];
  const float* Wsk = (const float*)d_in[6];
  const float* Wsv = (const float*)d_in[7];
  const float* Wso = (const float*)d_in[8];
  const float* Wrq = (const float*)d_in[9];
  const float* Wrk = (const float*)d_in[10];
  const float* Wrv = (const float*)d_in[11];
  const float* Wro = (const float*)d_in[12];

  float* outS = (float*)d_out;   // 1048576 fp32
  float* outR = outS + 1048576;  // 4194304 fp32

  // ---- workspace carve-up (~85 MB, no overlays) ----
  char* wp = (char*)d_ws;
  float* s_n32 = (float*)wp;                  wp += 1048576 * 4;   // 4 MB
  __hip_bfloat16* k    = (__hip_bfloat16*)wp; wp += 8388608 * 2;   // 16 MB
  __hip_bfloat16* v    = (__hip_bfloat16*)wp; wp += 8388608 * 2;   // 16 MB
  __hip_bfloat16* qrb  = (__hip_bfloat16*)wp; wp += 4194304 * 2;   // 8 MB
  __hip_bfloat16* krb  = (__hip_bfloat16*)wp; wp += 524288 * 2;    // 1 MB
  __hip_bfloat16* vrbT = (__hip_bfloat16*)wp; wp += 524288 * 2;    // 1 MB
  __hip_bfloat16* s_nb = (__hip_bfloat16*)wp; wp += 1048576 * 2;   // 2 MB
  __hip_bfloat16* r_nb = (__hip_bfloat16*)wp; wp += 4194304 * 2;   // 8 MB
  __hip_bfloat16* q    = (__hip_bfloat16*)wp; wp += 1048576 * 2;   // 2 MB
  __hip_bfloat16* attn1b = (__hip_bfloat16*)wp; wp += 1048576 * 2; // 2 MB
  __hip_bfloat16* ratb = (__hip_bfloat16*)wp; wp += 4194304 * 2;   // 8 MB
  float* Wc01 = (float*)wp;                   wp += 1048576 * 4;   // 4 MB (2 partials)
  float* u01  = (float*)wp;                   wp += 1048576 * 4;   // 4 MB (2 partials)
  __hip_bfloat16* WsqT = (__hip_bfloat16*)wp; wp += 1048576 * 2;
  __hip_bfloat16* WskT = (__hip_bfloat16*)wp; wp += 524288 * 2;
  __hip_bfloat16* WsvT = (__hip_bfloat16*)wp; wp += 524288 * 2;
  __hip_bfloat16* WsoT = (__hip_bfloat16*)wp; wp += 1048576 * 2;
  __hip_bfloat16* WrqT = (__hip_bfloat16*)wp; wp += 262144 * 2;
  __hip_bfloat16* WrkT = (__hip_bfloat16*)wp; wp += 524288 * 2;
  __hip_bfloat16* WrvT = (__hip_bfloat16*)wp; wp += 524288 * 2;
  __hip_bfloat16* WroT = (__hip_bfloat16*)wp; wp += 262144 * 2;

  float* u0 = u01;
  float* u1 = u01 + 524288;

  // 1) prep: transposes (Wrq pre-scaled 2^-3) + rmsnorms + Wc fp32 gemm
  TJobs jobs = {{
      {Wsq, WsqT, 1024, 1024, 1.f, 0},
      {Wsk, WskT, 512, 1024, 1.f, 1024},
      {Wsv, WsvT, 512, 1024, 1.f, 1536},
      {Wso, WsoT, 1024, 1024, 1.f, 2048},
      {Wrq, WrqT, 512, 512, 0.125f, 3072},
      {Wrk, WrkT, 1024, 512, 1.f, 3328},
      {Wrv, WrvT, 1024, 512, 1.f, 3840},
      {Wro, WroT, 512, 512, 1.f, 4352},
  }};
  prep_kernel<<<14080, 256, 0, stream>>>(jobs, s, r, nsw, nrw, s_nb, s_n32, r_nb,
                                         Wsq, Wsk, Wc01);

  // 2) merged: 6 bf16 MFMA gemms + u fp32 gemm (per-job XCD swizzle)
  GJobs6 g6 = {{
      {r_nb, WskT, k, 8192, 1024, 512, 0, 512, 0},
      {r_nb, WsvT, v, 8192, 1024, 512, 512, 512, 0},
      {r_nb, WrqT, qrb, 8192, 512, 512, 1024, 256, 0},
      {s_nb, WsqT, q, 1024, 1024, 1024, 1280, 64, 0},
      {s_nb, WrkT, krb, 1024, 512, 1024, 1344, 32, 0},
      {s_nb, WrvT, vrbT, 1024, 512, 1024, 1376, 32, 1},
  }};
  merged_gemm_kernel<<<1664, 256, 0, stream>>>(g6, s_n32, Wc01, u01);

  // 3) fused attention: flash (LPT+prefetch) + part1/part3
  fused_attn_kernel<<<2048, 256, 0, stream>>>(qrb, krb, vrbT, ratb, s, gv, q, k,
                                              v, r, nrw, u0, u1, attn1b, outS);

  // 4) epilogue: outS += attn1@Wso ; outR = r + rat@Wro
  epilogue_kernel<<<320, 256, 0, stream>>>(attn1b, WsoT, outS, ratb, WroT, outR, r);
}